// Round 10
// baseline (107.434 us; speedup 1.0000x reference)
//
#include <hip/hip_runtime.h>
#include <hip/hip_bf16.h>
#include <math.h>

#define N 4096
#define NGRP 16

typedef float f32x4 __attribute__((ext_vector_type(4)));

__inline__ __device__ float waveReduceSum(float v) {
    #pragma unroll
    for (int o = 32; o > 0; o >>= 1) v += __shfl_down(v, o);
    return v;
}

#define LD4(p, o) (*reinterpret_cast<const float4*>((p) + (o)))

__inline__ __device__ f32x4 ntld4(const float* p) {
    return __builtin_nontemporal_load(reinterpret_cast<const f32x4*>(p));
}

// Pure wh sweep (R7-verified ~50us): w/alpha nt (read-once streams), hebb normal.
template<int ITERS>
__global__ __launch_bounds__(256) void k_sweep_wh_t(const float* __restrict__ hid,
                                                    const float* __restrict__ w,
                                                    const float* __restrict__ alpha,
                                                    const float* __restrict__ hebb,
                                                    float* __restrict__ part,
                                                    int G) {
    int b = blockIdx.x, t = threadIdx.x;
    int p = b >> 2;
    int j0 = (((b & 3) << 8) | t) * 4;
    int P = G >> 2;
    size_t step = (size_t)G * 1024;
    size_t off = (size_t)(((b << 8) | t)) * 4;

    f32x4 wv[ITERS], av[ITERS], bv[ITERS];
    float hv[ITERS];
    #pragma unroll
    for (int k = 0; k < ITERS; ++k) {
        size_t o = off + (size_t)k * step;
        wv[k] = ntld4(w + o);
        av[k] = ntld4(alpha + o);
        bv[k] = *reinterpret_cast<const f32x4*>(hebb + o);
    }
    #pragma unroll
    for (int k = 0; k < ITERS; ++k) hv[k] = hid[k * P + p];

    f32x4 acc = {0.f, 0.f, 0.f, 0.f};
    #pragma unroll
    for (int k = 0; k < ITERS; ++k) {
        float h = hv[k];
        acc.x = fmaf(h, fmaf(av[k].x, bv[k].x, wv[k].x), acc.x);
        acc.y = fmaf(h, fmaf(av[k].y, bv[k].y, wv[k].y), acc.y);
        acc.z = fmaf(h, fmaf(av[k].z, bv[k].z, wv[k].z), acc.z);
        acc.w = fmaf(h, fmaf(av[k].w, bv[k].w, wv[k].w), acc.w);
    }
    *reinterpret_cast<f32x4*>(part + (size_t)p * N + j0) = acc;
}

// dynamic fallback (small workspace path)
__global__ __launch_bounds__(256) void k_sweep_wh(const float* __restrict__ hid,
                                                  const float* __restrict__ w,
                                                  const float* __restrict__ alpha,
                                                  const float* __restrict__ hebb,
                                                  float* __restrict__ part,
                                                  int G, int iters) {
    int b = blockIdx.x, t = threadIdx.x;
    int p = b >> 2;
    int j0 = (((b & 3) << 8) | t) * 4;
    int P = G >> 2;
    float4 acc = make_float4(0.f, 0.f, 0.f, 0.f);
    size_t step = (size_t)G * 1024;
    size_t off = (size_t)(((b << 8) | t)) * 4;
    #pragma unroll 8
    for (int k = 0; k < iters; ++k, off += step) {
        float h = hid[k * P + p];
        float4 wv = LD4(w, off);
        float4 av = LD4(alpha, off);
        float4 hv = LD4(hebb, off);
        acc.x = fmaf(h, fmaf(av.x, hv.x, wv.x), acc.x);
        acc.y = fmaf(h, fmaf(av.y, hv.y, wv.y), acc.y);
        acc.z = fmaf(h, fmaf(av.z, hv.z, wv.z), acc.z);
        acc.w = fmaf(h, fmaf(av.w, hv.w, wv.w), acc.w);
    }
    *reinterpret_cast<float4*>(part + (size_t)p * N + j0) = acc;
}

// Coalesced eta sweep: part[p][j] partials of sum_i wh[i]*pe[i][j], pe via nt.
template<int ITERS>
__global__ __launch_bounds__(256) void k_sweep_eta_t(const float* __restrict__ wh,
                                                     const float* __restrict__ pe,
                                                     float* __restrict__ part,
                                                     int G) {
    int b = blockIdx.x, t = threadIdx.x;
    int p = b >> 2;
    int j0 = (((b & 3) << 8) | t) * 4;
    int P = G >> 2;
    size_t step = (size_t)G * 1024;
    size_t off = (size_t)(((b << 8) | t)) * 4;

    f32x4 pv[ITERS];
    float hv[ITERS];
    #pragma unroll
    for (int k = 0; k < ITERS; ++k) pv[k] = ntld4(pe + off + (size_t)k * step);
    #pragma unroll
    for (int k = 0; k < ITERS; ++k) hv[k] = wh[k * P + p];

    f32x4 acc = {0.f, 0.f, 0.f, 0.f};
    #pragma unroll
    for (int k = 0; k < ITERS; ++k) {
        float h = hv[k];
        acc.x = fmaf(h, pv[k].x, acc.x);
        acc.y = fmaf(h, pv[k].y, acc.y);
        acc.z = fmaf(h, pv[k].z, acc.z);
        acc.w = fmaf(h, pv[k].w, acc.w);
    }
    *reinterpret_cast<f32x4*>(part + (size_t)p * N + j0) = acc;
}

__global__ __launch_bounds__(256) void k_sweep_eta(const float* __restrict__ wh,
                                                   const float* __restrict__ pe,
                                                   float* __restrict__ part,
                                                   int G, int iters) {
    int b = blockIdx.x, t = threadIdx.x;
    int p = b >> 2;
    int j0 = (((b & 3) << 8) | t) * 4;
    int P = G >> 2;
    float4 acc = make_float4(0.f, 0.f, 0.f, 0.f);
    size_t step = (size_t)G * 1024;
    size_t off = (size_t)(((b << 8) | t)) * 4;
    #pragma unroll 8
    for (int k = 0; k < iters; ++k, off += step) {
        float h = wh[k * P + p];
        float4 pv = LD4(pe, off);
        acc.x = fmaf(h, pv.x, acc.x);
        acc.y = fmaf(h, pv.y, acc.y);
        acc.z = fmaf(h, pv.z, acc.z);
        acc.w = fmaf(h, pv.w, acc.w);
    }
    *reinterpret_cast<float4*>(part + (size_t)p * N + j0) = acc;
}

// Fused: blocks [0, nred) reduce partials; blocks [nred, nred+N) wx rows (w_in nt).
__global__ __launch_bounds__(256) void k_red_wx(const float* __restrict__ part,
                                                float* __restrict__ part2,
                                                int cpg,
                                                const float* __restrict__ x,
                                                const float* __restrict__ w_in,
                                                float* __restrict__ wx_out,
                                                int nred) {
    int t = threadIdx.x;
    if ((int)blockIdx.x < nred) {
        int g  = blockIdx.x >> 2;
        int xt = blockIdx.x & 3;
        int j0 = (xt * 256 + t) * 4;
        const float4* p4 = reinterpret_cast<const float4*>(part);
        float4 s = make_float4(0.f, 0.f, 0.f, 0.f);
        #pragma unroll 8
        for (int c = 0; c < cpg; ++c) {
            float4 v = p4[((size_t)(g * cpg + c) * N + j0) >> 2];
            s.x += v.x; s.y += v.y; s.z += v.z; s.w += v.w;
        }
        *reinterpret_cast<float4*>(part2 + (size_t)g * N + j0) = s;
    } else {
        int j = blockIdx.x - nred;
        const float* row = w_in + (size_t)j * N;
        const float4* xv = reinterpret_cast<const float4*>(x);
        float sum = 0.f;
        #pragma unroll
        for (int k = t; k < N / 4; k += 256) {
            f32x4 a = ntld4(row + k * 4);
            float4 c = xv[k];
            sum += a.x * c.x + a.y * c.y + a.z * c.z + a.w * c.w;
        }
        sum = waveReduceSum(sum);
        __shared__ float wsum[4];
        int wid = t >> 6, lane = t & 63;
        if (lane == 0) wsum[wid] = sum;
        __syncthreads();
        if (t == 0)
            wx_out[j] = fmaxf(wsum[0] + wsum[1] + wsum[2] + wsum[3], 0.f);
    }
}

// plain reduce for eta partials
__global__ __launch_bounds__(256) void k_red(const float* __restrict__ part,
                                             float* __restrict__ part2,
                                             int cpg) {
    int g  = blockIdx.y;
    int j0 = (blockIdx.x * 256 + threadIdx.x) * 4;
    const float4* p4 = reinterpret_cast<const float4*>(part);
    float4 s = make_float4(0.f, 0.f, 0.f, 0.f);
    #pragma unroll 8
    for (int c = 0; c < cpg; ++c) {
        float4 v = p4[((size_t)(g * cpg + c) * N + j0) >> 2];
        s.x += v.x; s.y += v.y; s.z += v.z; s.w += v.w;
    }
    *reinterpret_cast<float4*>(part2 + (size_t)g * N + j0) = s;
}

// finalize wh from part2 (+b); s = wh + wx; LN; relu -> wy
__global__ __launch_bounds__(1024) void k_ln(const float* __restrict__ part2,
                                             const float* __restrict__ wx,
                                             const float* __restrict__ b,
                                             const float* __restrict__ gamma,
                                             const float* __restrict__ beta,
                                             float* __restrict__ wh_out,
                                             float* __restrict__ wy_out) {
    __shared__ float red[16];
    __shared__ float bc[2];
    int tid = threadIdx.x;
    int wid = tid >> 6, lane = tid & 63;
    float sv[4];
    float lsum = 0.f;
    #pragma unroll
    for (int q = 0; q < 4; ++q) {
        int j = q * 1024 + tid;
        float acc = b[j];
        #pragma unroll
        for (int g = 0; g < NGRP; ++g) acc += part2[(size_t)g * N + j];
        wh_out[j] = acc;
        float s = acc + wx[j];
        sv[q] = s;
        lsum += s;
    }
    float wv = waveReduceSum(lsum);
    if (lane == 0) red[wid] = wv;
    __syncthreads();
    if (tid < 64) {
        float t = (tid < 16) ? red[tid] : 0.f;
        t = waveReduceSum(t);
        if (tid == 0) bc[0] = t * (1.f / N);
    }
    __syncthreads();
    float mean = bc[0];
    __syncthreads();
    float lsq = 0.f;
    #pragma unroll
    for (int q = 0; q < 4; ++q) { float d = sv[q] - mean; lsq += d * d; }
    wv = waveReduceSum(lsq);
    if (lane == 0) red[wid] = wv;
    __syncthreads();
    if (tid < 64) {
        float t = (tid < 16) ? red[tid] : 0.f;
        t = waveReduceSum(t);
        if (tid == 0) bc[1] = t * (1.f / N);
    }
    __syncthreads();
    float rstd = rsqrtf(bc[1] + 1e-5f);
    #pragma unroll
    for (int q = 0; q < 4; ++q) {
        int j = q * 1024 + tid;
        float ln = fmaf(gamma[j] * (sv[q] - mean), rstd, beta[j]);
        wy_out[j] = fmaxf(ln, 0.f);
    }
}

// eta[j] = sigmoid(pb[j] + sum_g part2[g][j])
__global__ __launch_bounds__(256) void k_eta_fin(const float* __restrict__ part2,
                                                 const float* __restrict__ pb,
                                                 float* __restrict__ eta) {
    int j0 = (blockIdx.x * 256 + threadIdx.x) * 4;
    float4 s = *reinterpret_cast<const float4*>(pb + j0);
    #pragma unroll
    for (int g = 0; g < NGRP; ++g) {
        float4 v = *reinterpret_cast<const float4*>(part2 + (size_t)g * N + j0);
        s.x += v.x; s.y += v.y; s.z += v.z; s.w += v.w;
    }
    float4 r;
    r.x = 1.f / (1.f + expf(-s.x));
    r.y = 1.f / (1.f + expf(-s.y));
    r.z = 1.f / (1.f + expf(-s.z));
    r.w = 1.f / (1.f + expf(-s.w));
    *reinterpret_cast<float4*>(eta + j0) = r;
}

// hebb sweep update: hebb normal read (2nd read this replay -> best hit odds), nt write.
__global__ __launch_bounds__(256) void k_hebb(const float* __restrict__ hebb,
                                              const float* __restrict__ eta,
                                              const float* __restrict__ hid,
                                              const float* __restrict__ wh,
                                              const float* __restrict__ lamda,
                                              float* __restrict__ out,
                                              int G, int iters) {
    int b = blockIdx.x, t = threadIdx.x;
    int p = b >> 2;
    int P = G >> 2;
    int j0 = (((b & 3) << 8) | t) * 4;
    float decay = 1.f - lamda[0];
    float4 w4 = LD4(wh, j0);
    size_t step = (size_t)G * 1024;
    size_t off = (size_t)(((b << 8) | t)) * 4;
    #pragma unroll 8
    for (int k = 0; k < iters; ++k, off += step) {
        int i = k * P + p;
        float coef = eta[i] * hid[i];
        float4 h = LD4(hebb, off);
        f32x4 r;
        r.x = fmaf(decay, h.x, coef * w4.x);
        r.y = fmaf(decay, h.y, coef * w4.y);
        r.z = fmaf(decay, h.z, coef * w4.z);
        r.w = fmaf(decay, h.w, coef * w4.w);
        __builtin_nontemporal_store(r, reinterpret_cast<f32x4*>(out + off));
    }
}

extern "C" void kernel_launch(void* const* d_in, const int* in_sizes, int n_in,
                              void* d_out, int out_size, void* d_ws, size_t ws_size,
                              hipStream_t stream) {
    const float* x         = (const float*)d_in[0];
    const float* hid       = (const float*)d_in[1];
    const float* hebb      = (const float*)d_in[2];
    const float* w_in      = (const float*)d_in[3];
    const float* w         = (const float*)d_in[4];
    const float* alpha     = (const float*)d_in[5];
    const float* b         = (const float*)d_in[6];
    const float* lamda     = (const float*)d_in[7];
    const float* pred_eta  = (const float*)d_in[8];
    const float* pred_eta_b= (const float*)d_in[9];
    const float* ln_gamma  = (const float*)d_in[10];
    const float* ln_beta   = (const float*)d_in[11];

    float* wy       = (float*)d_out;
    float* hebb_out = (float*)d_out + N;

    int G = 2048;
    if ((ws_size / 4) < ((size_t)(G / 4) * N + (NGRP + 3) * (size_t)N)) G = 512;
    int P = G / 4;
    int cpg = P / NGRP;
    int iters = (N * (N / 4)) / (G * 256);
    int nred = 4 * NGRP;  // 64 reduction blocks

    float* ws    = (float*)d_ws;
    float* part  = ws;                          // P*N
    float* part2 = part + (size_t)P * N;        // NGRP*N
    float* wx    = part2 + (size_t)NGRP * N;    // N
    float* wh    = wx + N;                      // N
    float* eta   = wh + N;                      // N

    if (G == 2048) {
        k_sweep_wh_t<8><<<G, 256, 0, stream>>>(hid, w, alpha, hebb, part, G);
    } else {
        k_sweep_wh<<<G, 256, 0, stream>>>(hid, w, alpha, hebb, part, G, iters);
    }
    k_red_wx <<<nred + N, 256, 0, stream>>>(part, part2, cpg, x, w_in, wx, nred);
    k_ln     <<<1, 1024, 0, stream>>>(part2, wx, b, ln_gamma, ln_beta, wh, wy);
    if (G == 2048) {
        k_sweep_eta_t<8><<<G, 256, 0, stream>>>(wh, pred_eta, part, G);
    } else {
        k_sweep_eta<<<G, 256, 0, stream>>>(wh, pred_eta, part, G, iters);
    }
    k_red    <<<dim3(4, NGRP), 256, 0, stream>>>(part, part2, cpg);
    k_eta_fin<<<4, 256, 0, stream>>>(part2, pred_eta_b, eta);
    k_hebb   <<<G, 256, 0, stream>>>(hebb, eta, hid, wh, lamda, hebb_out, G, iters);
}

// Round 11
// 97.278 us; speedup vs baseline: 1.1044x; 1.1044x over previous
//
#include <hip/hip_runtime.h>
#include <hip/hip_bf16.h>
#include <math.h>

#define N 4096
#define NGRP 16

typedef float f32x4 __attribute__((ext_vector_type(4)));

__inline__ __device__ float waveReduceSum(float v) {
    #pragma unroll
    for (int o = 32; o > 0; o >>= 1) v += __shfl_down(v, o);
    return v;
}

#define LD4(p, o) (*reinterpret_cast<const float4*>((p) + (o)))

__inline__ __device__ f32x4 ntld4(const float* p) {
    return __builtin_nontemporal_load(reinterpret_cast<const f32x4*>(p));
}

// wh sweep (proven ~50us): w/alpha nt (read-once streams, no L3 alloc), hebb normal (keep resident).
template<int ITERS>
__global__ __launch_bounds__(256) void k_sweep_wh_t(const float* __restrict__ hid,
                                                    const float* __restrict__ w,
                                                    const float* __restrict__ alpha,
                                                    const float* __restrict__ hebb,
                                                    float* __restrict__ part,
                                                    int G) {
    int b = blockIdx.x, t = threadIdx.x;
    int p = b >> 2;
    int j0 = (((b & 3) << 8) | t) * 4;
    int P = G >> 2;
    size_t step = (size_t)G * 1024;
    size_t off = (size_t)(((b << 8) | t)) * 4;

    f32x4 wv[ITERS], av[ITERS], bv[ITERS];
    float hv[ITERS];
    #pragma unroll
    for (int k = 0; k < ITERS; ++k) {
        size_t o = off + (size_t)k * step;
        wv[k] = ntld4(w + o);
        av[k] = ntld4(alpha + o);
        bv[k] = *reinterpret_cast<const f32x4*>(hebb + o);
    }
    #pragma unroll
    for (int k = 0; k < ITERS; ++k) hv[k] = hid[k * P + p];

    f32x4 acc = {0.f, 0.f, 0.f, 0.f};
    #pragma unroll
    for (int k = 0; k < ITERS; ++k) {
        float h = hv[k];
        acc.x = fmaf(h, fmaf(av[k].x, bv[k].x, wv[k].x), acc.x);
        acc.y = fmaf(h, fmaf(av[k].y, bv[k].y, wv[k].y), acc.y);
        acc.z = fmaf(h, fmaf(av[k].z, bv[k].z, wv[k].z), acc.z);
        acc.w = fmaf(h, fmaf(av[k].w, bv[k].w, wv[k].w), acc.w);
    }
    *reinterpret_cast<f32x4*>(part + (size_t)p * N + j0) = acc;
}

// dynamic fallback (small workspace path)
__global__ __launch_bounds__(256) void k_sweep_wh(const float* __restrict__ hid,
                                                  const float* __restrict__ w,
                                                  const float* __restrict__ alpha,
                                                  const float* __restrict__ hebb,
                                                  float* __restrict__ part,
                                                  int G, int iters) {
    int b = blockIdx.x, t = threadIdx.x;
    int p = b >> 2;
    int j0 = (((b & 3) << 8) | t) * 4;
    int P = G >> 2;
    float4 acc = make_float4(0.f, 0.f, 0.f, 0.f);
    size_t step = (size_t)G * 1024;
    size_t off = (size_t)(((b << 8) | t)) * 4;
    #pragma unroll 8
    for (int k = 0; k < iters; ++k, off += step) {
        float h = hid[k * P + p];
        float4 wv = LD4(w, off);
        float4 av = LD4(alpha, off);
        float4 hv = LD4(hebb, off);
        acc.x = fmaf(h, fmaf(av.x, hv.x, wv.x), acc.x);
        acc.y = fmaf(h, fmaf(av.y, hv.y, wv.y), acc.y);
        acc.z = fmaf(h, fmaf(av.z, hv.z, wv.z), acc.z);
        acc.w = fmaf(h, fmaf(av.w, hv.w, wv.w), acc.w);
    }
    *reinterpret_cast<float4*>(part + (size_t)p * N + j0) = acc;
}

// eta sweep: NORMAL loads (pred_eta re-read every replay -> keep L3-resident).
template<int ITERS>
__global__ __launch_bounds__(256) void k_sweep_eta_t(const float* __restrict__ wh,
                                                     const float* __restrict__ pe,
                                                     float* __restrict__ part,
                                                     int G) {
    int b = blockIdx.x, t = threadIdx.x;
    int p = b >> 2;
    int j0 = (((b & 3) << 8) | t) * 4;
    int P = G >> 2;
    size_t step = (size_t)G * 1024;
    size_t off = (size_t)(((b << 8) | t)) * 4;

    f32x4 pv[ITERS];
    float hv[ITERS];
    #pragma unroll
    for (int k = 0; k < ITERS; ++k) pv[k] = *reinterpret_cast<const f32x4*>(pe + off + (size_t)k * step);
    #pragma unroll
    for (int k = 0; k < ITERS; ++k) hv[k] = wh[k * P + p];

    f32x4 acc = {0.f, 0.f, 0.f, 0.f};
    #pragma unroll
    for (int k = 0; k < ITERS; ++k) {
        float h = hv[k];
        acc.x = fmaf(h, pv[k].x, acc.x);
        acc.y = fmaf(h, pv[k].y, acc.y);
        acc.z = fmaf(h, pv[k].z, acc.z);
        acc.w = fmaf(h, pv[k].w, acc.w);
    }
    *reinterpret_cast<f32x4*>(part + (size_t)p * N + j0) = acc;
}

__global__ __launch_bounds__(256) void k_sweep_eta(const float* __restrict__ wh,
                                                   const float* __restrict__ pe,
                                                   float* __restrict__ part,
                                                   int G, int iters) {
    int b = blockIdx.x, t = threadIdx.x;
    int p = b >> 2;
    int j0 = (((b & 3) << 8) | t) * 4;
    int P = G >> 2;
    float4 acc = make_float4(0.f, 0.f, 0.f, 0.f);
    size_t step = (size_t)G * 1024;
    size_t off = (size_t)(((b << 8) | t)) * 4;
    #pragma unroll 8
    for (int k = 0; k < iters; ++k, off += step) {
        float h = wh[k * P + p];
        float4 pv = LD4(pe, off);
        acc.x = fmaf(h, pv.x, acc.x);
        acc.y = fmaf(h, pv.y, acc.y);
        acc.z = fmaf(h, pv.z, acc.z);
        acc.w = fmaf(h, pv.w, acc.w);
    }
    *reinterpret_cast<float4*>(part + (size_t)p * N + j0) = acc;
}

// Fused: blocks [0, nred) reduce wh partials; blocks [nred, nred+N) wx rows (w_in NORMAL -> L3-resident).
__global__ __launch_bounds__(256) void k_red_wx(const float* __restrict__ part,
                                                float* __restrict__ part2,
                                                int cpg,
                                                const float* __restrict__ x,
                                                const float* __restrict__ w_in,
                                                float* __restrict__ wx_out,
                                                int nred) {
    int t = threadIdx.x;
    if ((int)blockIdx.x < nred) {
        int g  = blockIdx.x >> 2;
        int xt = blockIdx.x & 3;
        int j0 = (xt * 256 + t) * 4;
        const float4* p4 = reinterpret_cast<const float4*>(part);
        float4 s = make_float4(0.f, 0.f, 0.f, 0.f);
        #pragma unroll 8
        for (int c = 0; c < cpg; ++c) {
            float4 v = p4[((size_t)(g * cpg + c) * N + j0) >> 2];
            s.x += v.x; s.y += v.y; s.z += v.z; s.w += v.w;
        }
        *reinterpret_cast<float4*>(part2 + (size_t)g * N + j0) = s;
    } else {
        int j = blockIdx.x - nred;
        const float4* row = reinterpret_cast<const float4*>(w_in + (size_t)j * N);
        const float4* xv  = reinterpret_cast<const float4*>(x);
        float sum = 0.f;
        #pragma unroll
        for (int k = t; k < N / 4; k += 256) {
            float4 a = row[k], c = xv[k];
            sum += a.x * c.x + a.y * c.y + a.z * c.z + a.w * c.w;
        }
        sum = waveReduceSum(sum);
        __shared__ float wsum[4];
        int wid = t >> 6, lane = t & 63;
        if (lane == 0) wsum[wid] = sum;
        __syncthreads();
        if (t == 0)
            wx_out[j] = fmaxf(wsum[0] + wsum[1] + wsum[2] + wsum[3], 0.f);
    }
}

// finalize wh from part2 (+b); s = wh + wx; LN; relu -> wy
__global__ __launch_bounds__(1024) void k_ln(const float* __restrict__ part2,
                                             const float* __restrict__ wx,
                                             const float* __restrict__ b,
                                             const float* __restrict__ gamma,
                                             const float* __restrict__ beta,
                                             float* __restrict__ wh_out,
                                             float* __restrict__ wy_out) {
    __shared__ float red[16];
    __shared__ float bc[2];
    int tid = threadIdx.x;
    int wid = tid >> 6, lane = tid & 63;
    float sv[4];
    float lsum = 0.f;
    #pragma unroll
    for (int q = 0; q < 4; ++q) {
        int j = q * 1024 + tid;
        float acc = b[j];
        #pragma unroll
        for (int g = 0; g < NGRP; ++g) acc += part2[(size_t)g * N + j];
        wh_out[j] = acc;
        float s = acc + wx[j];
        sv[q] = s;
        lsum += s;
    }
    float wv = waveReduceSum(lsum);
    if (lane == 0) red[wid] = wv;
    __syncthreads();
    if (tid < 64) {
        float t = (tid < 16) ? red[tid] : 0.f;
        t = waveReduceSum(t);
        if (tid == 0) bc[0] = t * (1.f / N);
    }
    __syncthreads();
    float mean = bc[0];
    __syncthreads();
    float lsq = 0.f;
    #pragma unroll
    for (int q = 0; q < 4; ++q) { float d = sv[q] - mean; lsq += d * d; }
    wv = waveReduceSum(lsq);
    if (lane == 0) red[wid] = wv;
    __syncthreads();
    if (tid < 64) {
        float t = (tid < 16) ? red[tid] : 0.f;
        t = waveReduceSum(t);
        if (tid == 0) bc[1] = t * (1.f / N);
    }
    __syncthreads();
    float rstd = rsqrtf(bc[1] + 1e-5f);
    #pragma unroll
    for (int q = 0; q < 4; ++q) {
        int j = q * 1024 + tid;
        float ln = fmaf(gamma[j] * (sv[q] - mean), rstd, beta[j]);
        wy_out[j] = fmaxf(ln, 0.f);
    }
}

// Fused eta-finalize + hebb update. 256 blocks x 1024 threads; block bk owns rows [bk*16, +16).
// Phase A: reduce eta partials for its 16 rows directly from `part` (P partials), + bias, sigmoid.
// Phase B: stream 16 hebb rows: out[i][j] = decay*hebb[i][j] + coef[i]*wh[j], nt store.
__global__ __launch_bounds__(1024) void k_redfin_hebb(const float* __restrict__ part,
                                                      const float* __restrict__ pb,
                                                      const float* __restrict__ wh,
                                                      const float* __restrict__ hid,
                                                      const float* __restrict__ lamda,
                                                      const float* __restrict__ hebb,
                                                      float* __restrict__ out,
                                                      int P) {
    __shared__ float sm[64][17];
    __shared__ float coef_s[16];
    int t  = threadIdx.x;
    int i0 = blockIdx.x * 16;
    int il = t & 15;          // which row/eta index within tile
    int ps = t >> 4;          // partial-slice 0..63
    int q  = P >> 6;          // partials per slice

    float s = 0.f;
    for (int k = 0; k < q; ++k)
        s += part[(size_t)(ps * q + k) * N + i0 + il];
    sm[ps][il] = s;
    __syncthreads();
    #pragma unroll
    for (int off = 32; off >= 1; off >>= 1) {
        if (ps < off) sm[ps][il] += sm[ps + off][il];
        __syncthreads();
    }
    if (t < 16) {
        int i = i0 + t;
        float eta = 1.f / (1.f + expf(-(sm[0][t] + pb[i])));
        coef_s[t] = eta * hid[i];
    }
    __syncthreads();

    float decay = 1.f - lamda[0];
    int j = t * 4;
    float4 w4 = LD4(wh, j);
    size_t base = (size_t)i0 * N + j;
    #pragma unroll 4
    for (int r = 0; r < 16; ++r) {
        float coef = coef_s[r];
        float4 h = LD4(hebb, base + (size_t)r * N);
        f32x4 o;
        o.x = fmaf(decay, h.x, coef * w4.x);
        o.y = fmaf(decay, h.y, coef * w4.y);
        o.z = fmaf(decay, h.z, coef * w4.z);
        o.w = fmaf(decay, h.w, coef * w4.w);
        __builtin_nontemporal_store(o, reinterpret_cast<f32x4*>(out + base + (size_t)r * N));
    }
}

extern "C" void kernel_launch(void* const* d_in, const int* in_sizes, int n_in,
                              void* d_out, int out_size, void* d_ws, size_t ws_size,
                              hipStream_t stream) {
    const float* x         = (const float*)d_in[0];
    const float* hid       = (const float*)d_in[1];
    const float* hebb      = (const float*)d_in[2];
    const float* w_in      = (const float*)d_in[3];
    const float* w         = (const float*)d_in[4];
    const float* alpha     = (const float*)d_in[5];
    const float* b         = (const float*)d_in[6];
    const float* lamda     = (const float*)d_in[7];
    const float* pred_eta  = (const float*)d_in[8];
    const float* pred_eta_b= (const float*)d_in[9];
    const float* ln_gamma  = (const float*)d_in[10];
    const float* ln_beta   = (const float*)d_in[11];

    float* wy       = (float*)d_out;
    float* hebb_out = (float*)d_out + N;

    int G = 2048;
    if ((ws_size / 4) < ((size_t)(G / 4) * N + (NGRP + 2) * (size_t)N)) G = 512;
    int P = G / 4;
    int cpg = P / NGRP;
    int iters = (N * (N / 4)) / (G * 256);
    int nred = 4 * NGRP;  // 64 reduction blocks

    float* ws    = (float*)d_ws;
    float* part  = ws;                          // P*N
    float* part2 = part + (size_t)P * N;        // NGRP*N
    float* wx    = part2 + (size_t)NGRP * N;    // N
    float* wh    = wx + N;                      // N

    if (G == 2048) {
        k_sweep_wh_t<8><<<G, 256, 0, stream>>>(hid, w, alpha, hebb, part, G);
    } else {
        k_sweep_wh<<<G, 256, 0, stream>>>(hid, w, alpha, hebb, part, G, iters);
    }
    k_red_wx<<<nred + N, 256, 0, stream>>>(part, part2, cpg, x, w_in, wx, nred);
    k_ln    <<<1, 1024, 0, stream>>>(part2, wx, b, ln_gamma, ln_beta, wh, wy);
    if (G == 2048) {
        k_sweep_eta_t<8><<<G, 256, 0, stream>>>(wh, pred_eta, part, G);
    } else {
        k_sweep_eta<<<G, 256, 0, stream>>>(wh, pred_eta, part, G, iters);
    }
    k_redfin_hebb<<<256, 1024, 0, stream>>>(part, pred_eta_b, wh, hid, lamda, hebb, hebb_out, P);
}

// Round 13
// 96.034 us; speedup vs baseline: 1.1187x; 1.0130x over previous
//
#include <hip/hip_runtime.h>
#include <hip/hip_cooperative_groups.h>
#include <hip/hip_bf16.h>
#include <math.h>

#define N 4096
#define NGRP 16

namespace cg = cooperative_groups;

typedef float f32x4 __attribute__((ext_vector_type(4)));

__inline__ __device__ float waveReduceSum(float v) {
    #pragma unroll
    for (int o = 32; o > 0; o >>= 1) v += __shfl_down(v, o);
    return v;
}

#define LD4(p, o) (*reinterpret_cast<const float4*>((p) + (o)))

__inline__ __device__ f32x4 ntld4(const float* p) {
    return __builtin_nontemporal_load(reinterpret_cast<const f32x4*>(p));
}

// ============================ cooperative fused kernel ============================
// G blocks x 256 threads, 4 blocks/CU. Phases separated by grid.sync().
template<int ITERS>
__global__ __launch_bounds__(256, 4) void k_coop(
    const float* __restrict__ x, const float* __restrict__ hid,
    const float* __restrict__ hebb, const float* __restrict__ w_in,
    const float* __restrict__ w, const float* __restrict__ alpha,
    const float* __restrict__ bvec, const float* __restrict__ lamda,
    const float* __restrict__ pe, const float* __restrict__ pb,
    const float* __restrict__ gamma, const float* __restrict__ beta,
    float* __restrict__ part, float* __restrict__ part2,
    float* __restrict__ wxv, float* __restrict__ whv,
    float* __restrict__ coef, float* __restrict__ wy,
    float* __restrict__ hebb_out, int G)
{
    cg::grid_group grid = cg::this_grid();
    const int b = blockIdx.x, t = threadIdx.x;
    const int P = G >> 2;
    const int lane = t & 63, wid = t >> 6;
    __shared__ float sm[16][17];
    __shared__ float smb[4];
    __shared__ float bc[2];

    // ---- P1a: wh partial sweep (w/alpha nt; hebb normal) ----
    {
        int p = b >> 2;
        int j0 = (((b & 3) << 8) | t) * 4;
        size_t step = (size_t)G * 1024;
        size_t off = (size_t)(((b << 8) | t)) * 4;
        f32x4 acc = {0.f, 0.f, 0.f, 0.f};
        #pragma unroll
        for (int h8 = 0; h8 < ITERS / 8; ++h8) {
            f32x4 wv[8], av[8], bv[8];
            float hv[8];
            #pragma unroll
            for (int k = 0; k < 8; ++k) {
                size_t o = off + (size_t)(h8 * 8 + k) * step;
                wv[k] = ntld4(w + o);
                av[k] = ntld4(alpha + o);
                bv[k] = *reinterpret_cast<const f32x4*>(hebb + o);
            }
            #pragma unroll
            for (int k = 0; k < 8; ++k) hv[k] = hid[(h8 * 8 + k) * P + p];
            #pragma unroll
            for (int k = 0; k < 8; ++k) {
                float h = hv[k];
                acc.x = fmaf(h, fmaf(av[k].x, bv[k].x, wv[k].x), acc.x);
                acc.y = fmaf(h, fmaf(av[k].y, bv[k].y, wv[k].y), acc.y);
                acc.z = fmaf(h, fmaf(av[k].z, bv[k].z, wv[k].z), acc.z);
                acc.w = fmaf(h, fmaf(av[k].w, bv[k].w, wv[k].w), acc.w);
            }
        }
        *reinterpret_cast<f32x4*>(part + (size_t)p * N + j0) = acc;
    }
    // ---- P1b: wx rows (L3-resident w_in, hides under sweep shadow) ----
    {
        int rpb = N / G;
        const float4* xv = reinterpret_cast<const float4*>(x);
        for (int r = 0; r < rpb; ++r) {
            int j = b * rpb + r;
            const float4* row = reinterpret_cast<const float4*>(w_in + (size_t)j * N);
            float sum = 0.f;
            #pragma unroll
            for (int c = 0; c < 4; ++c) {
                int k = t + c * 256;
                float4 a = row[k], xc = xv[k];
                sum += a.x * xc.x + a.y * xc.y + a.z * xc.z + a.w * xc.w;
            }
            sum = waveReduceSum(sum);
            if (lane == 0) smb[wid] = sum;
            __syncthreads();
            if (t == 0) wxv[j] = fmaxf(smb[0] + smb[1] + smb[2] + smb[3], 0.f);
            __syncthreads();
        }
    }
    grid.sync();

    // ---- P2: reduce part (P) -> part2 (NGRP) ----
    if (b < 4 * NGRP) {
        int g = b >> 2, xt = b & 3;
        int j0 = (xt * 256 + t) * 4;
        int cpg = P / NGRP;
        const f32x4* p4 = reinterpret_cast<const f32x4*>(part);
        f32x4 s = {0.f, 0.f, 0.f, 0.f};
        for (int c = 0; c < cpg; ++c) {
            f32x4 v = p4[((size_t)(g * cpg + c) * N + j0) >> 2];
            s.x += v.x; s.y += v.y; s.z += v.z; s.w += v.w;
        }
        *reinterpret_cast<f32x4*>(part2 + (size_t)g * N + j0) = s;
    }
    grid.sync();

    // ---- P3: wh finalize + LayerNorm (block 0) ----
    if (b == 0) {
        float sv[16];
        float lsum = 0.f;
        #pragma unroll
        for (int q = 0; q < 16; ++q) {
            int j = q * 256 + t;
            float acc = bvec[j];
            #pragma unroll
            for (int g = 0; g < NGRP; ++g) acc += part2[(size_t)g * N + j];
            whv[j] = acc;
            float s = acc + wxv[j];
            sv[q] = s;
            lsum += s;
        }
        float wr = waveReduceSum(lsum);
        if (lane == 0) smb[wid] = wr;
        __syncthreads();
        if (t == 0) bc[0] = (smb[0] + smb[1] + smb[2] + smb[3]) * (1.f / N);
        __syncthreads();
        float mean = bc[0];
        float lsq = 0.f;
        #pragma unroll
        for (int q = 0; q < 16; ++q) { float d = sv[q] - mean; lsq += d * d; }
        float wr2 = waveReduceSum(lsq);
        if (lane == 0) smb[wid] = wr2;
        __syncthreads();
        if (t == 0) bc[1] = (smb[0] + smb[1] + smb[2] + smb[3]) * (1.f / N);
        __syncthreads();
        float rstd = rsqrtf(bc[1] + 1e-5f);
        #pragma unroll
        for (int q = 0; q < 16; ++q) {
            int j = q * 256 + t;
            float ln = fmaf(gamma[j] * (sv[q] - mean), rstd, beta[j]);
            wy[j] = fmaxf(ln, 0.f);
        }
    }
    grid.sync();

    // ---- P4: eta partial sweep (pe normal -> L3-resident) ----
    {
        int p = b >> 2;
        int j0 = (((b & 3) << 8) | t) * 4;
        size_t step = (size_t)G * 1024;
        size_t off = (size_t)(((b << 8) | t)) * 4;
        f32x4 acc = {0.f, 0.f, 0.f, 0.f};
        #pragma unroll
        for (int h8 = 0; h8 < ITERS / 8; ++h8) {
            f32x4 pv[8];
            float hv[8];
            #pragma unroll
            for (int k = 0; k < 8; ++k)
                pv[k] = *reinterpret_cast<const f32x4*>(pe + off + (size_t)(h8 * 8 + k) * step);
            #pragma unroll
            for (int k = 0; k < 8; ++k) hv[k] = whv[(h8 * 8 + k) * P + p];
            #pragma unroll
            for (int k = 0; k < 8; ++k) {
                float h = hv[k];
                acc.x = fmaf(h, pv[k].x, acc.x);
                acc.y = fmaf(h, pv[k].y, acc.y);
                acc.z = fmaf(h, pv[k].z, acc.z);
                acc.w = fmaf(h, pv[k].w, acc.w);
            }
        }
        *reinterpret_cast<f32x4*>(part + (size_t)p * N + j0) = acc;
    }
    grid.sync();

    // ---- P5: eta finalize -> coef (blocks 0..255) ----
    if (b < 256) {
        int i0 = b * 16;
        int il = t & 15, ps = t >> 4;   // 16 slices of 16 partials
        int q2 = P >> 4;
        float s = 0.f;
        for (int k = 0; k < q2; ++k)
            s += part[(size_t)(ps * q2 + k) * N + i0 + il];
        sm[ps][il] = s;
        __syncthreads();
        #pragma unroll
        for (int off2 = 8; off2 >= 1; off2 >>= 1) {
            if (ps < off2) sm[ps][il] += sm[ps + off2][il];
            __syncthreads();
        }
        if (t < 16) {
            int i = i0 + t;
            float eta = 1.f / (1.f + expf(-(sm[0][t] + pb[i])));
            coef[i] = eta * hid[i];
        }
    }
    grid.sync();

    // ---- P6: hebb stream update (normal read, nt write) ----
    {
        float decay = 1.f - lamda[0];
        int rpb = N / G;
        for (int r = 0; r < rpb; ++r) {
            int i = b * rpb + r;
            float cf = coef[i];
            size_t base = (size_t)i * N;
            const f32x4* hrow = reinterpret_cast<const f32x4*>(hebb + base);
            f32x4* orow = reinterpret_cast<f32x4*>(hebb_out + base);
            const f32x4* wrow = reinterpret_cast<const f32x4*>(whv);
            #pragma unroll
            for (int c = 0; c < 4; ++c) {
                int k = t + c * 256;
                f32x4 h = hrow[k];
                f32x4 wv4 = wrow[k];
                f32x4 o;
                o.x = fmaf(decay, h.x, cf * wv4.x);
                o.y = fmaf(decay, h.y, cf * wv4.y);
                o.z = fmaf(decay, h.z, cf * wv4.z);
                o.w = fmaf(decay, h.w, cf * wv4.w);
                __builtin_nontemporal_store(o, orow + k);
            }
        }
    }
}

// ============================ fallback kernels (R11, proven 97us) ============================
template<int ITERS>
__global__ __launch_bounds__(256) void k_sweep_wh_t(const float* __restrict__ hid,
                                                    const float* __restrict__ w,
                                                    const float* __restrict__ alpha,
                                                    const float* __restrict__ hebb,
                                                    float* __restrict__ part,
                                                    int G) {
    int b = blockIdx.x, t = threadIdx.x;
    int p = b >> 2;
    int j0 = (((b & 3) << 8) | t) * 4;
    int P = G >> 2;
    size_t step = (size_t)G * 1024;
    size_t off = (size_t)(((b << 8) | t)) * 4;
    f32x4 wv[ITERS], av[ITERS], bv[ITERS];
    float hv[ITERS];
    #pragma unroll
    for (int k = 0; k < ITERS; ++k) {
        size_t o = off + (size_t)k * step;
        wv[k] = ntld4(w + o);
        av[k] = ntld4(alpha + o);
        bv[k] = *reinterpret_cast<const f32x4*>(hebb + o);
    }
    #pragma unroll
    for (int k = 0; k < ITERS; ++k) hv[k] = hid[k * P + p];
    f32x4 acc = {0.f, 0.f, 0.f, 0.f};
    #pragma unroll
    for (int k = 0; k < ITERS; ++k) {
        float h = hv[k];
        acc.x = fmaf(h, fmaf(av[k].x, bv[k].x, wv[k].x), acc.x);
        acc.y = fmaf(h, fmaf(av[k].y, bv[k].y, wv[k].y), acc.y);
        acc.z = fmaf(h, fmaf(av[k].z, bv[k].z, wv[k].z), acc.z);
        acc.w = fmaf(h, fmaf(av[k].w, bv[k].w, wv[k].w), acc.w);
    }
    *reinterpret_cast<f32x4*>(part + (size_t)p * N + j0) = acc;
}

template<int ITERS>
__global__ __launch_bounds__(256) void k_sweep_eta_t(const float* __restrict__ wh,
                                                     const float* __restrict__ pe,
                                                     float* __restrict__ part,
                                                     int G) {
    int b = blockIdx.x, t = threadIdx.x;
    int p = b >> 2;
    int j0 = (((b & 3) << 8) | t) * 4;
    int P = G >> 2;
    size_t step = (size_t)G * 1024;
    size_t off = (size_t)(((b << 8) | t)) * 4;
    f32x4 pv[ITERS];
    float hv[ITERS];
    #pragma unroll
    for (int k = 0; k < ITERS; ++k) pv[k] = *reinterpret_cast<const f32x4*>(pe + off + (size_t)k * step);
    #pragma unroll
    for (int k = 0; k < ITERS; ++k) hv[k] = wh[k * P + p];
    f32x4 acc = {0.f, 0.f, 0.f, 0.f};
    #pragma unroll
    for (int k = 0; k < ITERS; ++k) {
        float h = hv[k];
        acc.x = fmaf(h, pv[k].x, acc.x);
        acc.y = fmaf(h, pv[k].y, acc.y);
        acc.z = fmaf(h, pv[k].z, acc.z);
        acc.w = fmaf(h, pv[k].w, acc.w);
    }
    *reinterpret_cast<f32x4*>(part + (size_t)p * N + j0) = acc;
}

__global__ __launch_bounds__(256) void k_red_wx(const float* __restrict__ part,
                                                float* __restrict__ part2,
                                                int cpg,
                                                const float* __restrict__ x,
                                                const float* __restrict__ w_in,
                                                float* __restrict__ wx_out,
                                                int nred) {
    int t = threadIdx.x;
    if ((int)blockIdx.x < nred) {
        int g  = blockIdx.x >> 2;
        int xt = blockIdx.x & 3;
        int j0 = (xt * 256 + t) * 4;
        const float4* p4 = reinterpret_cast<const float4*>(part);
        float4 s = make_float4(0.f, 0.f, 0.f, 0.f);
        #pragma unroll 8
        for (int c = 0; c < cpg; ++c) {
            float4 v = p4[((size_t)(g * cpg + c) * N + j0) >> 2];
            s.x += v.x; s.y += v.y; s.z += v.z; s.w += v.w;
        }
        *reinterpret_cast<float4*>(part2 + (size_t)g * N + j0) = s;
    } else {
        int j = blockIdx.x - nred;
        const float4* row = reinterpret_cast<const float4*>(w_in + (size_t)j * N);
        const float4* xv  = reinterpret_cast<const float4*>(x);
        float sum = 0.f;
        #pragma unroll
        for (int k = t; k < N / 4; k += 256) {
            float4 a = row[k], c = xv[k];
            sum += a.x * c.x + a.y * c.y + a.z * c.z + a.w * c.w;
        }
        sum = waveReduceSum(sum);
        __shared__ float wsum[4];
        int wid = t >> 6, lane = t & 63;
        if (lane == 0) wsum[wid] = sum;
        __syncthreads();
        if (t == 0)
            wx_out[j] = fmaxf(wsum[0] + wsum[1] + wsum[2] + wsum[3], 0.f);
    }
}

__global__ __launch_bounds__(1024) void k_ln(const float* __restrict__ part2,
                                             const float* __restrict__ wx,
                                             const float* __restrict__ b,
                                             const float* __restrict__ gamma,
                                             const float* __restrict__ beta,
                                             float* __restrict__ wh_out,
                                             float* __restrict__ wy_out) {
    __shared__ float red[16];
    __shared__ float bc[2];
    int tid = threadIdx.x;
    int wid = tid >> 6, lane = tid & 63;
    float sv[4];
    float lsum = 0.f;
    #pragma unroll
    for (int q = 0; q < 4; ++q) {
        int j = q * 1024 + tid;
        float acc = b[j];
        #pragma unroll
        for (int g = 0; g < NGRP; ++g) acc += part2[(size_t)g * N + j];
        wh_out[j] = acc;
        float s = acc + wx[j];
        sv[q] = s;
        lsum += s;
    }
    float wv = waveReduceSum(lsum);
    if (lane == 0) red[wid] = wv;
    __syncthreads();
    if (tid < 64) {
        float t = (tid < 16) ? red[tid] : 0.f;
        t = waveReduceSum(t);
        if (tid == 0) bc[0] = t * (1.f / N);
    }
    __syncthreads();
    float mean = bc[0];
    __syncthreads();
    float lsq = 0.f;
    #pragma unroll
    for (int q = 0; q < 4; ++q) { float d = sv[q] - mean; lsq += d * d; }
    wv = waveReduceSum(lsq);
    if (lane == 0) red[wid] = wv;
    __syncthreads();
    if (tid < 64) {
        float t = (tid < 16) ? red[tid] : 0.f;
        t = waveReduceSum(t);
        if (tid == 0) bc[1] = t * (1.f / N);
    }
    __syncthreads();
    float rstd = rsqrtf(bc[1] + 1e-5f);
    #pragma unroll
    for (int q = 0; q < 4; ++q) {
        int j = q * 1024 + tid;
        float ln = fmaf(gamma[j] * (sv[q] - mean), rstd, beta[j]);
        wy_out[j] = fmaxf(ln, 0.f);
    }
}

__global__ __launch_bounds__(1024) void k_redfin_hebb(const float* __restrict__ part,
                                                      const float* __restrict__ pb,
                                                      const float* __restrict__ wh,
                                                      const float* __restrict__ hid,
                                                      const float* __restrict__ lamda,
                                                      const float* __restrict__ hebb,
                                                      float* __restrict__ out,
                                                      int P) {
    __shared__ float sm[64][17];
    __shared__ float coef_s[16];
    int t  = threadIdx.x;
    int i0 = blockIdx.x * 16;
    int il = t & 15;
    int ps = t >> 4;
    int q  = P >> 6;

    float s = 0.f;
    for (int k = 0; k < q; ++k)
        s += part[(size_t)(ps * q + k) * N + i0 + il];
    sm[ps][il] = s;
    __syncthreads();
    #pragma unroll
    for (int off = 32; off >= 1; off >>= 1) {
        if (ps < off) sm[ps][il] += sm[ps + off][il];
        __syncthreads();
    }
    if (t < 16) {
        int i = i0 + t;
        float eta = 1.f / (1.f + expf(-(sm[0][t] + pb[i])));
        coef_s[t] = eta * hid[i];
    }
    __syncthreads();

    float decay = 1.f - lamda[0];
    int j = t * 4;
    float4 w4 = LD4(wh, j);
    size_t base = (size_t)i0 * N + j;
    #pragma unroll 4
    for (int r = 0; r < 16; ++r) {
        float coef = coef_s[r];
        float4 h = LD4(hebb, base + (size_t)r * N);
        f32x4 o;
        o.x = fmaf(decay, h.x, coef * w4.x);
        o.y = fmaf(decay, h.y, coef * w4.y);
        o.z = fmaf(decay, h.z, coef * w4.z);
        o.w = fmaf(decay, h.w, coef * w4.w);
        __builtin_nontemporal_store(o, reinterpret_cast<f32x4*>(out + base + (size_t)r * N));
    }
}

extern "C" void kernel_launch(void* const* d_in, const int* in_sizes, int n_in,
                              void* d_out, int out_size, void* d_ws, size_t ws_size,
                              hipStream_t stream) {
    const float* x         = (const float*)d_in[0];
    const float* hid       = (const float*)d_in[1];
    const float* hebb      = (const float*)d_in[2];
    const float* w_in      = (const float*)d_in[3];
    const float* w         = (const float*)d_in[4];
    const float* alpha     = (const float*)d_in[5];
    const float* bvec      = (const float*)d_in[6];
    const float* lamda     = (const float*)d_in[7];
    const float* pred_eta  = (const float*)d_in[8];
    const float* pred_eta_b= (const float*)d_in[9];
    const float* ln_gamma  = (const float*)d_in[10];
    const float* ln_beta   = (const float*)d_in[11];

    float* wy       = (float*)d_out;
    float* hebb_out = (float*)d_out + N;

    // ---------- try cooperative path: G=1024, 4 blocks/CU ----------
    const int Gc = 1024;
    const int Pc = Gc / 4;   // 256 partials
    bool wsOK = (ws_size / 4) >= ((size_t)Pc * N + (size_t)(NGRP + 3) * N);

    int dev = 0;
    hipGetDevice(&dev);
    int coopAttr = 0, numCU = 0;
    hipDeviceGetAttribute(&coopAttr, hipDeviceAttributeCooperativeLaunch, dev);
    hipDeviceGetAttribute(&numCU, hipDeviceAttributeMultiprocessorCount, dev);
    int maxB = 0;
    hipOccupancyMaxActiveBlocksPerMultiprocessor(&maxB, (const void*)&k_coop<16>, 256, 0);

    if (coopAttr && wsOK && maxB > 0 && (size_t)maxB * (size_t)numCU >= (size_t)Gc) {
        float* ws    = (float*)d_ws;
        float* part  = ws;                          // Pc*N
        float* part2 = part + (size_t)Pc * N;       // NGRP*N
        float* wxv   = part2 + (size_t)NGRP * N;    // N
        float* whv   = wxv + N;                     // N
        float* coef  = whv + N;                     // N
        int Gl = Gc;
        void* args[] = {
            (void*)&x, (void*)&hid, (void*)&hebb, (void*)&w_in, (void*)&w,
            (void*)&alpha, (void*)&bvec, (void*)&lamda, (void*)&pred_eta,
            (void*)&pred_eta_b, (void*)&ln_gamma, (void*)&ln_beta,
            (void*)&part, (void*)&part2, (void*)&wxv, (void*)&whv,
            (void*)&coef, (void*)&wy, (void*)&hebb_out, (void*)&Gl
        };
        hipError_t err = hipLaunchCooperativeKernel((const void*)&k_coop<16>,
                                                    dim3(Gc), dim3(256), args, 0, stream);
        if (err == hipSuccess) return;
        // fall through to multi-kernel path on failure
    }

    // ---------- fallback: R11 multi-kernel path (proven) ----------
    int G = 2048;
    int P = G / 4;
    int cpg = P / NGRP;
    int nred = 4 * NGRP;

    float* ws    = (float*)d_ws;
    float* part  = ws;
    float* part2 = part + (size_t)P * N;
    float* wxv   = part2 + (size_t)NGRP * N;
    float* whv   = wxv + N;

    k_sweep_wh_t<8><<<G, 256, 0, stream>>>(hid, w, alpha, hebb, part, G);
    k_red_wx<<<nred + N, 256, 0, stream>>>(part, part2, cpg, x, w_in, wxv, nred);
    k_ln    <<<1, 1024, 0, stream>>>(part2, wxv, bvec, ln_gamma, ln_beta, whv, wy);
    k_sweep_eta_t<8><<<G, 256, 0, stream>>>(whv, pred_eta, part, G);
    k_redfin_hebb<<<256, 1024, 0, stream>>>(part, pred_eta_b, whv, hid, lamda, hebb, hebb_out, P);
}